// Round 1
// baseline (453.654 us; speedup 1.0000x reference)
//
#include <hip/hip_runtime.h>
#include <math.h>

// GAT layer fused kernel, fp32 correctness-first version.
// N=8192 nodes, IN=512, D=64. ALPHA=0.2.
//
// ws layout (floats):
//   h    : [8192][64]                   524288
//   s1   : [8192]                         8192
//   s2   : [8192]                         8192
//   numP : [1024 blocks][64 r][64 d]   4194304   (it*8+jc blocks)
//   denP : [1024 blocks][64 r]           65536
// total ~18.3 MB

#define NN 8192
#define KIN 512
#define DD 64
#define ALPHA 0.2f

// ---------------- Kernel 1: h = X @ W  (fp32 tiled GEMM) ----------------
// 128 blocks x 256 threads; block computes 64 rows x 64 dims; 4x4 reg tile.
__global__ __launch_bounds__(256) void k_gemm_h(const float* __restrict__ X,
                                                const float* __restrict__ W,
                                                float* __restrict__ h) {
    __shared__ __align__(16) float XT[32 * 68];  // [k][row], stride 68 keeps 16B align + bank spread
    __shared__ __align__(16) float WL[32 * 64];  // [k][d]
    const int t = threadIdx.x;
    const int i0 = blockIdx.x * 64;
    const int rb = t >> 4, db = t & 15;  // accum role: rows rb*4.., dims db*4..
    float acc[4][4] = {};

    for (int k0 = 0; k0 < KIN; k0 += 32) {
        // stage X tile transposed: 64 rows x 32 k
        {
            const int kq = t & 7;    // k quad
            const int rr = t >> 3;   // 0..31
#pragma unroll
            for (int p = 0; p < 2; ++p) {
                const int row = p * 32 + rr;
                const float4 x4 = *(const float4*)(X + (size_t)(i0 + row) * KIN + k0 + kq * 4);
                XT[(kq * 4 + 0) * 68 + row] = x4.x;
                XT[(kq * 4 + 1) * 68 + row] = x4.y;
                XT[(kq * 4 + 2) * 68 + row] = x4.z;
                XT[(kq * 4 + 3) * 68 + row] = x4.w;
            }
            // stage W tile: 32 k x 64 d
#pragma unroll
            for (int p = 0; p < 2; ++p) {
                const int q = p * 256 + t;  // float4 index 0..511
                const int kk = q >> 4, dq = q & 15;
                *(float4*)(WL + kk * 64 + dq * 4) =
                    *(const float4*)(W + (size_t)(k0 + kk) * DD + dq * 4);
            }
        }
        __syncthreads();
#pragma unroll
        for (int k = 0; k < 32; ++k) {
            const float4 a4 = *(const float4*)(XT + k * 68 + rb * 4);
            const float4 b4 = *(const float4*)(WL + k * 64 + db * 4);
            const float av[4] = {a4.x, a4.y, a4.z, a4.w};
            const float bv[4] = {b4.x, b4.y, b4.z, b4.w};
#pragma unroll
            for (int i = 0; i < 4; ++i)
#pragma unroll
                for (int j = 0; j < 4; ++j) acc[i][j] += av[i] * bv[j];
        }
        __syncthreads();
    }
#pragma unroll
    for (int i = 0; i < 4; ++i) {
        float4 o = {acc[i][0], acc[i][1], acc[i][2], acc[i][3]};
        *(float4*)(h + (size_t)(i0 + rb * 4 + i) * DD + db * 4) = o;
    }
}

// ---------------- Kernel 2: s1/s2 = h @ a1, h @ a2 ----------------
// one wave per row; lane d holds h[r][d].
__global__ __launch_bounds__(256) void k_s12(const float* __restrict__ h,
                                             const float* __restrict__ a,
                                             float* __restrict__ s1,
                                             float* __restrict__ s2) {
    const int lane = threadIdx.x & 63;
    const int w = threadIdx.x >> 6;
    const int r = blockIdx.x * 4 + w;
    const float v = h[(size_t)r * DD + lane];
    float p1 = v * a[lane];
    float p2 = v * a[64 + lane];
#pragma unroll
    for (int off = 32; off; off >>= 1) {
        p1 += __shfl_xor(p1, off, 64);
        p2 += __shfl_xor(p2, off, 64);
    }
    if (lane == 0) {
        s1[r] = p1;
        s2[r] = p2;
    }
}

// ---------------- Kernel 3: fused masked-softmax-weighted sum (partials) ----------------
// grid = 128 i-tiles x 8 j-chunks = 1024 blocks, 256 threads.
// Per block: rows i0..i0+63, j in [jc*1024, jc*1024+1024), windows of 64 j.
__global__ __launch_bounds__(256) void k_attn(const float* __restrict__ h,
                                              const int* __restrict__ Adj,
                                              const float* __restrict__ s1,
                                              const float* __restrict__ s2,
                                              float* __restrict__ numP,
                                              float* __restrict__ denP) {
    __shared__ __align__(16) float ET[64 * 65];  // [jl][row], stride 65: 2-way bank alias = free
    __shared__ __align__(16) float HL[64 * 64];  // [jj][d]
    const int t = threadIdx.x;
    const int it = blockIdx.x >> 3;
    const int jc = blockIdx.x & 7;
    const int i0 = it * 64;
    const int jb0 = jc * 1024;
    const int jl = t & 63, rg = t >> 6;  // E-phase role: wave rg owns rows rg*16..+15
    const int rb = t >> 4, db = t & 15;  // accum role: 4x4 reg tile

    float s1v[16];
#pragma unroll
    for (int rr = 0; rr < 16; ++rr) s1v[rr] = s1[i0 + rg * 16 + rr];
    float dd[16] = {};      // per-(row, jl-lane) denominator partials
    float nn[4][4] = {};    // num accumulators

    for (int w = 0; w < 16; ++w) {
        const int jb = jb0 + w * 64;
        // stage h window [64 j][64 d]
#pragma unroll
        for (int p = 0; p < 4; ++p) {
            const int q = p * 256 + t;  // float4 index 0..1023
            *(float4*)(HL + q * 4) = *(const float4*)(h + (size_t)jb * DD + q * 4);
        }
        // compute E tile
        const float s2l = s2[jb + jl];
        const int* adjp = Adj + (size_t)(i0 + rg * 16) * NN + jb + jl;
#pragma unroll
        for (int rr = 0; rr < 16; ++rr) {
            const int adj = adjp[(size_t)rr * NN];
            const float s = s1v[rr] + s2l;
            const float l = s > 0.f ? s : ALPHA * s;
            float e = __expf(l);
            e = (adj != 0) ? e : 0.f;
            ET[jl * 65 + rg * 16 + rr] = e;
            dd[rr] += e;
        }
        __syncthreads();
        // accumulate num += E * h over this window
#pragma unroll 8
        for (int jj = 0; jj < 64; ++jj) {
            const float4 hv = *(const float4*)(HL + jj * 64 + db * 4);
            const float e0 = ET[jj * 65 + rb * 4 + 0];
            const float e1 = ET[jj * 65 + rb * 4 + 1];
            const float e2 = ET[jj * 65 + rb * 4 + 2];
            const float e3 = ET[jj * 65 + rb * 4 + 3];
            nn[0][0] += e0 * hv.x; nn[0][1] += e0 * hv.y; nn[0][2] += e0 * hv.z; nn[0][3] += e0 * hv.w;
            nn[1][0] += e1 * hv.x; nn[1][1] += e1 * hv.y; nn[1][2] += e1 * hv.z; nn[1][3] += e1 * hv.w;
            nn[2][0] += e2 * hv.x; nn[2][1] += e2 * hv.y; nn[2][2] += e2 * hv.z; nn[2][3] += e2 * hv.w;
            nn[3][0] += e3 * hv.x; nn[3][1] += e3 * hv.y; nn[3][2] += e3 * hv.z; nn[3][3] += e3 * hv.w;
        }
        __syncthreads();
    }
    // write num partials
    const size_t base = (size_t)blockIdx.x * 64 * 64;
#pragma unroll
    for (int i = 0; i < 4; ++i) {
        float4 o = {nn[i][0], nn[i][1], nn[i][2], nn[i][3]};
        *(float4*)(numP + base + (size_t)(rb * 4 + i) * 64 + db * 4) = o;
    }
    // reduce denominator partials over jl lanes (wave rg owns rows rg*16..+15)
#pragma unroll
    for (int rr = 0; rr < 16; ++rr) {
        float v = dd[rr];
#pragma unroll
        for (int off = 32; off; off >>= 1) v += __shfl_xor(v, off, 64);
        if (jl == 0) denP[(size_t)blockIdx.x * 64 + rg * 16 + rr] = v;
    }
}

// ---------------- Kernel 4: reduce partials + normalize ----------------
__global__ __launch_bounds__(256) void k_final(const float* __restrict__ numP,
                                               const float* __restrict__ denP,
                                               float* __restrict__ out) {
    const int idx = blockIdx.x * 256 + threadIdx.x;  // 0..524287
    const int i = idx >> 6, d = idx & 63;
    const int it = i >> 6, r = i & 63;
    float num = 0.f, den = 0.f;
#pragma unroll
    for (int c = 0; c < 8; ++c) {
        const size_t bx = (size_t)(it * 8 + c);
        num += numP[bx * 4096 + (size_t)r * 64 + d];
        den += denP[bx * 64 + r];
    }
    out[idx] = num / den;
}

extern "C" void kernel_launch(void* const* d_in, const int* in_sizes, int n_in,
                              void* d_out, int out_size, void* d_ws, size_t ws_size,
                              hipStream_t stream) {
    const float* X = (const float*)d_in[0];
    const int* Adj = (const int*)d_in[1];
    const float* W = (const float*)d_in[2];
    const float* a = (const float*)d_in[3];
    float* out = (float*)d_out;

    float* ws = (float*)d_ws;
    float* h = ws;                     // 524288
    float* s1 = h + 524288;            // 8192
    float* s2 = s1 + 8192;             // 8192
    float* numP = s2 + 8192;           // 1024*4096
    float* denP = numP + 1024 * 4096;  // 1024*64

    k_gemm_h<<<128, 256, 0, stream>>>(X, W, h);
    k_s12<<<2048, 256, 0, stream>>>(h, a, s1, s2);
    k_attn<<<1024, 256, 0, stream>>>(h, Adj, s1, s2, numP, denP);
    k_final<<<2048, 256, 0, stream>>>(numP, denP, out);
}

// Round 2
// 432.342 us; speedup vs baseline: 1.0493x; 1.0493x over previous
//
#include <hip/hip_runtime.h>
#include <math.h>

// GAT layer, round 2: MFMA attention, LDS-free k_attn.
// N=8192, IN=512, D=64, ALPHA=0.2
//
// ws layout (float units):
//   h     : [8192][64] f32            524288
//   s1    : [8192] f32                  8192
//   s2    : [8192] f32                  8192
//   hFrag : [256 jblk][4 dt][64 lane] bf16x8 = 524288 bf16 = 262144 float-slots
//   numP  : [1024][64][64] f32       4194304
//   denP  : [1024][64] f32             65536
// total ~20.3 MB

#define NN 8192
#define KIN 512
#define DD 64
#define ALPHA 0.2f

using floatx4 = __attribute__((ext_vector_type(4))) float;
using bf16x8  = __attribute__((ext_vector_type(8))) __bf16;

// ---------------- Kernel 1: h = X @ W (fp32, 256 blocks x 32 rows) ----------------
__global__ __launch_bounds__(256) void k_gemm_h(const float* __restrict__ X,
                                                const float* __restrict__ W,
                                                float* __restrict__ h) {
    __shared__ __align__(16) float XT[32 * 36];  // [k][row], stride 36
    __shared__ __align__(16) float WL[32 * 64];  // [k][d]
    const int t = threadIdx.x;
    const int i0 = blockIdx.x * 32;
    const int rb = t >> 5;   // rows rb*4..+3
    const int db = t & 31;   // dims db*2..+1
    float acc[4][2] = {};

    for (int k0 = 0; k0 < KIN; k0 += 32) {
        {
            const int row = t >> 3, kq = t & 7;
            const float4 x4 = *(const float4*)(X + (size_t)(i0 + row) * KIN + k0 + kq * 4);
            XT[(kq * 4 + 0) * 36 + row] = x4.x;
            XT[(kq * 4 + 1) * 36 + row] = x4.y;
            XT[(kq * 4 + 2) * 36 + row] = x4.z;
            XT[(kq * 4 + 3) * 36 + row] = x4.w;
#pragma unroll
            for (int p = 0; p < 2; ++p) {
                const int q = p * 256 + t;  // 0..511
                const int kk = q >> 4, dq = q & 15;
                *(float4*)(WL + kk * 64 + dq * 4) =
                    *(const float4*)(W + (size_t)(k0 + kk) * DD + dq * 4);
            }
        }
        __syncthreads();
#pragma unroll
        for (int k = 0; k < 32; ++k) {
            const float4 xa = *(const float4*)(XT + k * 36 + rb * 4);
            const float2 wb = *(const float2*)(WL + k * 64 + db * 2);
            const float xv[4] = {xa.x, xa.y, xa.z, xa.w};
#pragma unroll
            for (int i = 0; i < 4; ++i) {
                acc[i][0] += xv[i] * wb.x;
                acc[i][1] += xv[i] * wb.y;
            }
        }
        __syncthreads();
    }
#pragma unroll
    for (int i = 0; i < 4; ++i) {
        float2 o = {acc[i][0], acc[i][1]};
        *(float2*)(h + (size_t)(i0 + rb * 4 + i) * DD + db * 2) = o;
    }
}

// ---------------- Kernel 2: s1/s2 = h @ a1, h @ a2 ----------------
__global__ __launch_bounds__(256) void k_s12(const float* __restrict__ h,
                                             const float* __restrict__ a,
                                             float* __restrict__ s1,
                                             float* __restrict__ s2) {
    const int lane = threadIdx.x & 63;
    const int w = threadIdx.x >> 6;
    const int r = blockIdx.x * 4 + w;
    const float v = h[(size_t)r * DD + lane];
    float p1 = v * a[lane];
    float p2 = v * a[64 + lane];
#pragma unroll
    for (int off = 32; off; off >>= 1) {
        p1 += __shfl_xor(p1, off, 64);
        p2 += __shfl_xor(p2, off, 64);
    }
    if (lane == 0) {
        s1[r] = p1;
        s2[r] = p2;
    }
}

// ---------------- Kernel 3: pack h into MFMA B-fragments (bf16) ----------------
// hFrag[jblk][dt][lane][jj] = bf16( h[jblk*32 + (lane>>4)*8 + jj][dt*16 + (lane&15)] )
__global__ __launch_bounds__(256) void k_hfrag(const float* __restrict__ h,
                                               __bf16* __restrict__ hFrag) {
    const int f = blockIdx.x * 256 + threadIdx.x;  // 0..65535
    const int lane = f & 63, dt = (f >> 6) & 3, jblk = f >> 8;
    const int n = lane & 15, q = lane >> 4;
    bf16x8 v;
#pragma unroll
    for (int jj = 0; jj < 8; ++jj)
        v[jj] = (__bf16)h[(size_t)(jblk * 32 + q * 8 + jj) * DD + dt * 16 + n];
    *(bf16x8*)(hFrag + (size_t)f * 8) = v;
}

// ---------------- Kernel 4: fused masked-softmax numerator via MFMA ----------------
// grid = 128 i-tiles x 8 j-chunks = 1024 blocks, 256 threads (4 waves), NO LDS.
// Wave w owns rows i0 + w*16 .. +15 across all 64 dims (4 d-tiles).
__global__ __launch_bounds__(256) void k_attn2(const bf16x8* __restrict__ hFrag,
                                               const int* __restrict__ Adj,
                                               const float* __restrict__ s1,
                                               const float* __restrict__ s2,
                                               float* __restrict__ numP,
                                               float* __restrict__ denP) {
    const int t = threadIdx.x;
    const int wv = t >> 6;
    const int lane = t & 63;
    const int n = lane & 15, q = lane >> 4;
    const int it = blockIdx.x >> 3, jc = blockIdx.x & 7;
    const int i0 = it * 64;
    const int row = i0 + wv * 16 + n;  // E-row this lane produces (A-frag m index)
    const float s1v = s1[row];
    const int jbase = jc * 1024;

    floatx4 acc[4] = {};  // 4 d-tiles, C/D layout: col = dt*16+n, row(m) = q*4+reg
    float den = 0.f;

    const int* adjRow = Adj + (size_t)row * NN;

    for (int ks = 0; ks < 32; ++ks) {
        const int j0 = jbase + ks * 32;
        const int jq = j0 + q * 8;  // this lane's 8 j values
        const int4 a0 = *(const int4*)(adjRow + jq);
        const int4 a1 = *(const int4*)(adjRow + jq + 4);
        const float4 z0 = *(const float4*)(s2 + jq);
        const float4 z1 = *(const float4*)(s2 + jq + 4);
        const int adjv[8] = {a0.x, a0.y, a0.z, a0.w, a1.x, a1.y, a1.z, a1.w};
        const float s2v[8] = {z0.x, z0.y, z0.z, z0.w, z1.x, z1.y, z1.z, z1.w};
        bf16x8 af;
#pragma unroll
        for (int u = 0; u < 8; ++u) {
            const float s = s1v + s2v[u];
            const float l = fmaxf(s, ALPHA * s);  // leaky-relu (alpha<1)
            float e = __expf(l);
            e = adjv[u] ? e : 0.f;
            den += e;
            af[u] = (__bf16)e;
        }
        const bf16x8* hf = hFrag + ((size_t)(j0 >> 5) * 4) * 64 + lane;
#pragma unroll
        for (int dt = 0; dt < 4; ++dt) {
            const bf16x8 bf = hf[dt * 64];
            acc[dt] = __builtin_amdgcn_mfma_f32_16x16x32_bf16(af, bf, acc[dt], 0, 0, 0);
        }
    }

    // write numerator partials: D row m = q*4+reg, col = dt*16+n
    const size_t base = (size_t)blockIdx.x * 4096;
#pragma unroll
    for (int dt = 0; dt < 4; ++dt)
#pragma unroll
        for (int r = 0; r < 4; ++r)
            numP[base + (size_t)(wv * 16 + q * 4 + r) * 64 + dt * 16 + n] = acc[dt][r];

    // denominator: sum the 4 q-quads that share row n
    den += __shfl_xor(den, 16, 64);
    den += __shfl_xor(den, 32, 64);
    if (q == 0) denP[(size_t)blockIdx.x * 64 + wv * 16 + n] = den;
}

// ---------------- Kernel 5: reduce partials + normalize ----------------
__global__ __launch_bounds__(256) void k_final(const float* __restrict__ numP,
                                               const float* __restrict__ denP,
                                               float* __restrict__ out) {
    const int idx = blockIdx.x * 256 + threadIdx.x;  // 0..524287
    const int i = idx >> 6, d = idx & 63;
    const int it = i >> 6, r = i & 63;
    float num = 0.f, den = 0.f;
#pragma unroll
    for (int c = 0; c < 8; ++c) {
        const size_t bx = (size_t)(it * 8 + c);
        num += numP[bx * 4096 + (size_t)r * 64 + d];
        den += denP[bx * 64 + r];
    }
    out[idx] = num / den;
}

extern "C" void kernel_launch(void* const* d_in, const int* in_sizes, int n_in,
                              void* d_out, int out_size, void* d_ws, size_t ws_size,
                              hipStream_t stream) {
    const float* X = (const float*)d_in[0];
    const int* Adj = (const int*)d_in[1];
    const float* W = (const float*)d_in[2];
    const float* a = (const float*)d_in[3];
    float* out = (float*)d_out;

    float* ws = (float*)d_ws;
    float* h = ws;                       // 524288
    float* s1 = h + 524288;              // 8192
    float* s2 = s1 + 8192;               // 8192
    __bf16* hFrag = (__bf16*)(s2 + 8192);  // 524288 bf16 (= 262144 float slots)
    float* numP = s2 + 8192 + 262144;    // 1024*4096
    float* denP = numP + 1024 * 4096;    // 1024*64

    k_gemm_h<<<256, 256, 0, stream>>>(X, W, h);
    k_s12<<<2048, 256, 0, stream>>>(h, a, s1, s2);
    k_hfrag<<<256, 256, 0, stream>>>(h, hFrag);
    k_attn2<<<1024, 256, 0, stream>>>((const bf16x8*)hFrag, Adj, s1, s2, numP, denP);
    k_final<<<2048, 256, 0, stream>>>(numP, denP, out);
}

// Round 3
// 419.087 us; speedup vs baseline: 1.0825x; 1.0316x over previous
//
#include <hip/hip_runtime.h>
#include <math.h>

// GAT layer, round 3: MFMA attention with row-contiguous Adj streaming and
// barrier-free wave-private LDS transpose.
// N=8192, IN=512, D=64, ALPHA=0.2
//
// ws layout (float units):
//   h     : [8192][64] f32            524288
//   s1    : [8192] f32                  8192
//   s2    : [8192] f32                  8192
//   hFrag : [256 jblk][4 dt][64 lane] bf16x8 = 524288 bf16 = 262144 float-slots
//   numP  : [1024][64][64] f32       4194304
//   denP  : [1024][64] f32             65536

#define NN 8192
#define KIN 512
#define DD 64
#define ALPHA 0.2f

using floatx4 = __attribute__((ext_vector_type(4))) float;
using bf16x8  = __attribute__((ext_vector_type(8))) __bf16;
using bf16x4  = __attribute__((ext_vector_type(4))) __bf16;

// ---------------- Kernel 1: h = X @ W (fp32, 256 blocks x 32 rows) ----------------
__global__ __launch_bounds__(256) void k_gemm_h(const float* __restrict__ X,
                                                const float* __restrict__ W,
                                                float* __restrict__ h) {
    __shared__ __align__(16) float XT[32 * 36];  // [k][row], stride 36
    __shared__ __align__(16) float WL[32 * 64];  // [k][d]
    const int t = threadIdx.x;
    const int i0 = blockIdx.x * 32;
    const int rb = t >> 5;   // rows rb*4..+3
    const int db = t & 31;   // dims db*2..+1
    float acc[4][2] = {};

    for (int k0 = 0; k0 < KIN; k0 += 32) {
        {
            const int row = t >> 3, kq = t & 7;
            const float4 x4 = *(const float4*)(X + (size_t)(i0 + row) * KIN + k0 + kq * 4);
            XT[(kq * 4 + 0) * 36 + row] = x4.x;
            XT[(kq * 4 + 1) * 36 + row] = x4.y;
            XT[(kq * 4 + 2) * 36 + row] = x4.z;
            XT[(kq * 4 + 3) * 36 + row] = x4.w;
#pragma unroll
            for (int p = 0; p < 2; ++p) {
                const int q = p * 256 + t;  // 0..511
                const int kk = q >> 4, dq = q & 15;
                *(float4*)(WL + kk * 64 + dq * 4) =
                    *(const float4*)(W + (size_t)(k0 + kk) * DD + dq * 4);
            }
        }
        __syncthreads();
#pragma unroll
        for (int k = 0; k < 32; ++k) {
            const float4 xa = *(const float4*)(XT + k * 36 + rb * 4);
            const float2 wb = *(const float2*)(WL + k * 64 + db * 2);
            const float xv[4] = {xa.x, xa.y, xa.z, xa.w};
#pragma unroll
            for (int i = 0; i < 4; ++i) {
                acc[i][0] += xv[i] * wb.x;
                acc[i][1] += xv[i] * wb.y;
            }
        }
        __syncthreads();
    }
#pragma unroll
    for (int i = 0; i < 4; ++i) {
        float2 o = {acc[i][0], acc[i][1]};
        *(float2*)(h + (size_t)(i0 + rb * 4 + i) * DD + db * 2) = o;
    }
}

// ---------------- Kernel 2: s1/s2 = h @ a1, h @ a2 ----------------
__global__ __launch_bounds__(256) void k_s12(const float* __restrict__ h,
                                             const float* __restrict__ a,
                                             float* __restrict__ s1,
                                             float* __restrict__ s2) {
    const int lane = threadIdx.x & 63;
    const int w = threadIdx.x >> 6;
    const int r = blockIdx.x * 4 + w;
    const float v = h[(size_t)r * DD + lane];
    float p1 = v * a[lane];
    float p2 = v * a[64 + lane];
#pragma unroll
    for (int off = 32; off; off >>= 1) {
        p1 += __shfl_xor(p1, off, 64);
        p2 += __shfl_xor(p2, off, 64);
    }
    if (lane == 0) {
        s1[r] = p1;
        s2[r] = p2;
    }
}

// ---------------- Kernel 3: pack h into MFMA B-fragments (bf16) ----------------
// hFrag[jblk][dt][lane][jj] = bf16( h[jblk*32 + (lane>>4)*8 + jj][dt*16 + (lane&15)] )
__global__ __launch_bounds__(256) void k_hfrag(const float* __restrict__ h,
                                               __bf16* __restrict__ hFrag) {
    const int f = blockIdx.x * 256 + threadIdx.x;  // 0..65535
    const int lane = f & 63, dt = (f >> 6) & 3, jblk = f >> 8;
    const int n = lane & 15, q = lane >> 4;
    bf16x8 v;
#pragma unroll
    for (int jj = 0; jj < 8; ++jj)
        v[jj] = (__bf16)h[(size_t)(jblk * 32 + q * 8 + jj) * DD + dt * 16 + n];
    *(bf16x8*)(hFrag + (size_t)f * 8) = v;
}

// ---------------- Kernel 4: fused masked-softmax numerator via MFMA ----------------
// grid = 128 i-tiles x 8 j-chunks = 1024 blocks, 256 threads (4 waves).
// Wave wv owns rows i0+wv*16..+15. Per 256-j window:
//   stage: 16 row-contiguous 1KB Adj loads -> exp/mask -> bf16 -> wave-private LDS
//   mfma : 8 K-steps of 16x16x32, A from LDS, B (hFrag) from L2, + ones-B for den
// NO __syncthreads anywhere (each wave reads only its own LDS writes).
__global__ __launch_bounds__(256, 4) void k_attn3(const bf16x8* __restrict__ hFrag,
                                                  const int* __restrict__ Adj,
                                                  const float* __restrict__ s1,
                                                  const float* __restrict__ s2,
                                                  float* __restrict__ numP,
                                                  float* __restrict__ denP) {
    // stride 264 bf16 (528 B): write banks 2-way (free); b128 frag reads perfectly balanced
    __shared__ __align__(16) __bf16 ET[4][16][264];
    const int t = threadIdx.x;
    const int wv = t >> 6;
    const int lane = t & 63;
    const int n = lane & 15, q = lane >> 4;
    const int it = blockIdx.x >> 3, jc = blockIdx.x & 7;
    const int i0 = it * 64;

    float s1v[16];
#pragma unroll
    for (int rr = 0; rr < 16; ++rr) s1v[rr] = s1[i0 + wv * 16 + rr];

    bf16x8 ones;
#pragma unroll
    for (int u = 0; u < 8; ++u) ones[u] = (__bf16)1.0f;

    floatx4 acc[5] = {};  // 4 d-tiles + denominator (B = ones)

    const int* adjBase = Adj + (size_t)(i0 + wv * 16) * NN + jc * 1024 + lane * 4;

    for (int w = 0; w < 4; ++w) {
        const int j0 = jc * 1024 + w * 256;
        // s2 window: lane's 4 consecutive j (same for all 16 rows)
        const float4 z = *(const float4*)(s2 + j0 + lane * 4);
        // ---- stage 16 rows, 4 at a time (4 KB in flight per wave) ----
#pragma unroll
        for (int pass = 0; pass < 4; ++pass) {
            int4 av[4];
#pragma unroll
            for (int r4 = 0; r4 < 4; ++r4)
                av[r4] = *(const int4*)(adjBase + (size_t)(pass * 4 + r4) * NN + w * 256);
#pragma unroll
            for (int r4 = 0; r4 < 4; ++r4) {
                const int rr = pass * 4 + r4;
                const float s1r = s1v[rr];
                const int am[4] = {av[r4].x, av[r4].y, av[r4].z, av[r4].w};
                const float zz[4] = {z.x, z.y, z.z, z.w};
                bf16x4 ev;
#pragma unroll
                for (int c = 0; c < 4; ++c) {
                    const float s = s1r + zz[c];
                    const float l = fmaxf(s, ALPHA * s);
                    float e = __expf(l);
                    e = am[c] ? e : 0.f;
                    ev[c] = (__bf16)e;
                }
                *(bf16x4*)&ET[wv][rr][lane * 4] = ev;
            }
        }
        // ---- MFMA over this window: 8 K-steps of 32 j ----
        const int jblk0 = j0 >> 5;
#pragma unroll
        for (int ks = 0; ks < 8; ++ks) {
            const bf16x8 af = *(const bf16x8*)&ET[wv][n][ks * 32 + q * 8];
            const bf16x8* hf = hFrag + ((size_t)(jblk0 + ks) * 4) * 64 + lane;
#pragma unroll
            for (int dt = 0; dt < 4; ++dt)
                acc[dt] = __builtin_amdgcn_mfma_f32_16x16x32_bf16(af, hf[dt * 64], acc[dt], 0, 0, 0);
            acc[4] = __builtin_amdgcn_mfma_f32_16x16x32_bf16(af, ones, acc[4], 0, 0, 0);
        }
    }

    // numerator partials: D row m = q*4+reg, col = dt*16+n
    const size_t base = (size_t)blockIdx.x * 4096;
#pragma unroll
    for (int dt = 0; dt < 4; ++dt)
#pragma unroll
        for (int r = 0; r < 4; ++r)
            numP[base + (size_t)(wv * 16 + q * 4 + r) * 64 + dt * 16 + n] = acc[dt][r];

    // denominator: every col of acc[4] holds the row-sum; lane n==0 writes its 4 rows
    if (n == 0) {
#pragma unroll
        for (int r = 0; r < 4; ++r)
            denP[(size_t)blockIdx.x * 64 + wv * 16 + q * 4 + r] = acc[4][r];
    }
}

// ---------------- Kernel 5: reduce partials + normalize ----------------
__global__ __launch_bounds__(256) void k_final(const float* __restrict__ numP,
                                               const float* __restrict__ denP,
                                               float* __restrict__ out) {
    const int idx = blockIdx.x * 256 + threadIdx.x;  // 0..524287
    const int i = idx >> 6, d = idx & 63;
    const int it = i >> 6, r = i & 63;
    float num = 0.f, den = 0.f;
#pragma unroll
    for (int c = 0; c < 8; ++c) {
        const size_t bx = (size_t)(it * 8 + c);
        num += numP[bx * 4096 + (size_t)r * 64 + d];
        den += denP[bx * 64 + r];
    }
    out[idx] = num / den;
}

extern "C" void kernel_launch(void* const* d_in, const int* in_sizes, int n_in,
                              void* d_out, int out_size, void* d_ws, size_t ws_size,
                              hipStream_t stream) {
    const float* X = (const float*)d_in[0];
    const int* Adj = (const int*)d_in[1];
    const float* W = (const float*)d_in[2];
    const float* a = (const float*)d_in[3];
    float* out = (float*)d_out;

    float* ws = (float*)d_ws;
    float* h = ws;                         // 524288
    float* s1 = h + 524288;                // 8192
    float* s2 = s1 + 8192;                 // 8192
    __bf16* hFrag = (__bf16*)(s2 + 8192);  // 524288 bf16 (= 262144 float slots)
    float* numP = s2 + 8192 + 262144;      // 1024*4096
    float* denP = numP + 1024 * 4096;      // 1024*64

    k_gemm_h<<<256, 256, 0, stream>>>(X, W, h);
    k_s12<<<2048, 256, 0, stream>>>(h, a, s1, s2);
    k_hfrag<<<256, 256, 0, stream>>>(h, hFrag);
    k_attn3<<<1024, 256, 0, stream>>>((const bf16x8*)hFrag, Adj, s1, s2, numP, denP);
    k_final<<<2048, 256, 0, stream>>>(numP, denP, out);
}